// Round 10
// baseline (1191.631 us; speedup 1.0000x reference)
//
#include <hip/hip_runtime.h>
#include <math.h>

// Problem constants (fixed by the reference)
#define NN      32768
#define EE_N    262144
#define LL      4
#define HID     512
#define IN_DIM  386
#define KP_IN   416      // IN_DIM padded to multiple of 32
#define OUT_DIM 384
#define EDIM    32
#define MAX_SP  4

typedef __attribute__((ext_vector_type(8))) __bf16 bf16x8;
typedef __attribute__((ext_vector_type(4))) float  f32x4;

// ---------------------------------------------------------------------------
// bf16 helpers (bit-level, RNE)
// ---------------------------------------------------------------------------
__device__ __forceinline__ unsigned short f2bf(float f) {
    unsigned int u = __float_as_uint(f);
    unsigned int r = (u + 0x7FFFu + ((u >> 16) & 1u)) >> 16;
    return (unsigned short)r;
}
__device__ __forceinline__ void unpack2(unsigned int w, float& lo, float& hi) {
    lo = __uint_as_float(w << 16);
    hi = __uint_as_float(w & 0xFFFF0000u);
}
__device__ __forceinline__ void unpack8(const uint4& v, float* f) {
    unpack2(v.x, f[0], f[1]); unpack2(v.y, f[2], f[3]);
    unpack2(v.z, f[4], f[5]); unpack2(v.w, f[6], f[7]);
}

// ---------------------------------------------------------------------------
// MFMA GEMM: C[M,N] = A[M,Kp](bf16) @ Bt[N,Kp](bf16)^T + bias[N](f32)
// 128x128 tile, BK=32, 4 waves, each wave 64x64 via 4x4 frags of 16x16x32.
// global_load_lds width=16 staging; LDS slot-swizzle on the GLOBAL source
// (dest linear, G21), matched on ds_read -> 2-way banking (free).
// Chunked-bijective XCD swizzle (nwg%8==0 for all our grids).
// OUT_MODE: 0 = f32 C0;  1 = bf16 C0;  2 = f32 C0 + bf16 C1.
// ldc = C row stride in elements (strided writes into wide qkv layouts).
// ---------------------------------------------------------------------------
template <int OUT_MODE>
__global__ __launch_bounds__(256) void gemm_mfma(
    const unsigned short* __restrict__ A,   // [M][Kp] bf16 row-major
    const unsigned short* __restrict__ Bt,  // [N][Kp] bf16 (W transposed)
    const float* __restrict__ bias,
    void* __restrict__ C0, void* __restrict__ C1,
    int M, int Kp, int N, int ldc)
{
    __shared__ unsigned short As[128 * 32];  // row r at byte r*64, 4 slots of 16B
    __shared__ unsigned short Bs[128 * 32];  // col c at byte c*64

    const int t    = threadIdx.x;
    const int lane = t & 63, wid = t >> 6;
    const int wr   = wid >> 1, wc = wid & 1;        // 2x2 wave grid

    // XCD-aware chunked swizzle (bijective when nwg % 8 == 0)
    const int nwg = gridDim.x * gridDim.y;
    int bid = blockIdx.y * gridDim.x + blockIdx.x;
    if ((nwg & 7) == 0) bid = (bid & 7) * (nwg >> 3) + (bid >> 3);
    const int row0 = (bid / gridDim.x) * 128;
    const int col0 = (bid % gridDim.x) * 128;

    f32x4 acc[4][4] = {};

    const int srow  = lane >> 2;   // staging: 4 lanes per row (4x16B = 64B row)
    const int sslot = lane & 3;
    const int kq    = lane >> 4;   // ds_read k-quarter (0..3)
    const int l15   = lane & 15;

    for (int kt = 0; kt < Kp; kt += 32) {
#pragma unroll
        for (int i = 0; i < 2; ++i) {
            const int rbase = wid * 32 + i * 16;
            {   // A tile rows [rbase, rbase+16)
                const int r    = rbase + srow;
                const int koff = sslot ^ ((r >> 1) & 3);
                const unsigned short* ga = &A[(size_t)(row0 + r) * Kp + kt + koff * 8];
                __builtin_amdgcn_global_load_lds(
                    (const __attribute__((address_space(1))) unsigned int*)ga,
                    (__attribute__((address_space(3))) unsigned int*)&As[rbase * 32],
                    16, 0, 0);
            }
            {   // B tile cols [rbase, rbase+16)
                const int c    = rbase + srow;
                const int koff = sslot ^ ((c >> 1) & 3);
                const unsigned short* gb = &Bt[(size_t)(col0 + c) * Kp + kt + koff * 8];
                __builtin_amdgcn_global_load_lds(
                    (const __attribute__((address_space(1))) unsigned int*)gb,
                    (__attribute__((address_space(3))) unsigned int*)&Bs[rbase * 32],
                    16, 0, 0);
            }
        }
        __syncthreads();   // compiler drains vmcnt+lgkmcnt before s_barrier

        bf16x8 af[4], bfr[4];
#pragma unroll
        for (int mi = 0; mi < 4; ++mi) {
            const int r    = wr * 64 + mi * 16 + l15;
            const int slot = kq ^ ((r >> 1) & 3);
            af[mi] = *reinterpret_cast<const bf16x8*>(&As[r * 32 + slot * 8]);
        }
#pragma unroll
        for (int ni = 0; ni < 4; ++ni) {
            const int c    = wc * 64 + ni * 16 + l15;
            const int slot = kq ^ ((c >> 1) & 3);
            bfr[ni] = *reinterpret_cast<const bf16x8*>(&Bs[c * 32 + slot * 8]);
        }
#pragma unroll
        for (int mi = 0; mi < 4; ++mi)
#pragma unroll
            for (int ni = 0; ni < 4; ++ni)
                acc[mi][ni] = __builtin_amdgcn_mfma_f32_16x16x32_bf16(
                    af[mi], bfr[ni], acc[mi][ni], 0, 0, 0);
        __syncthreads();
    }

    // epilogue: D frag layout col=lane&15, row=(lane>>4)*4+r  [m89-verified]
    const int cb = col0 + wc * 64;
    const int rb = row0 + wr * 64;
    float bv[4];
#pragma unroll
    for (int ni = 0; ni < 4; ++ni) bv[ni] = bias[cb + ni * 16 + l15];

#pragma unroll
    for (int mi = 0; mi < 4; ++mi) {
#pragma unroll
        for (int ni = 0; ni < 4; ++ni) {
            const int col = cb + ni * 16 + l15;
#pragma unroll
            for (int r = 0; r < 4; ++r) {
                const int row = rb + mi * 16 + kq * 4 + r;
                const float oval = acc[mi][ni][r] + bv[ni];
                if (OUT_MODE == 0) {
                    ((float*)C0)[(size_t)row * ldc + col] = oval;
                } else if (OUT_MODE == 1) {
                    ((unsigned short*)C0)[(size_t)row * ldc + col] = f2bf(oval);
                } else {
                    ((float*)C0)[(size_t)row * ldc + col] = oval;
                    ((unsigned short*)C1)[(size_t)row * ldc + col] = f2bf(oval);
                }
            }
        }
    }
}

// ---------------------------------------------------------------------------
// Weight convert+transpose: Wt[n][k] = bf16(W[k][n]), zero-pad k in [K, Kp)
// ---------------------------------------------------------------------------
__global__ __launch_bounds__(256) void convert_wt(
    const float* __restrict__ W, unsigned short* __restrict__ Wt,
    int K, int N, int Kp)
{
    __shared__ float tile[32][33];
    const int tx = threadIdx.x, ty = threadIdx.y;
    const int kb = blockIdx.y * 32, nb = blockIdx.x * 32;
#pragma unroll
    for (int i = 0; i < 32; i += 8) {
        const int k = kb + ty + i, n = nb + tx;
        tile[ty + i][tx] = (k < K && n < N) ? W[(size_t)k * N + n] : 0.f;
    }
    __syncthreads();
#pragma unroll
    for (int i = 0; i < 32; i += 8) {
        const int n = nb + ty + i, k = kb + tx;
        if (n < N && k < Kp)
            Wt[(size_t)n * Kp + k] = f2bf(tile[tx][ty + i]);
    }
}

// Batched: all 16 per-layer HID x HID weights in one launch.
// blockIdx.z = l*4 + t, t in {q,k,v,s}; output at Wlt + z*HID*HID.
__global__ __launch_bounds__(256) void convert_wt_batch(
    const float* __restrict__ Wq, const float* __restrict__ Wk,
    const float* __restrict__ Wv, const float* __restrict__ Ws,
    unsigned short* __restrict__ Wlt)
{
    __shared__ float tile[32][33];
    const int m = blockIdx.z;
    const int l = m >> 2, tp = m & 3;
    const float* W = (tp == 0 ? Wq : tp == 1 ? Wk : tp == 2 ? Wv : Ws)
                     + (size_t)l * HID * HID;
    unsigned short* Wt = Wlt + (size_t)m * HID * HID;
    const int tx = threadIdx.x, ty = threadIdx.y;
    const int kb = blockIdx.y * 32, nb = blockIdx.x * 32;
#pragma unroll
    for (int i = 0; i < 32; i += 8)
        tile[ty + i][tx] = W[(size_t)(kb + ty + i) * HID + nb + tx];
    __syncthreads();
#pragma unroll
    for (int i = 0; i < 32; i += 8)
        Wt[(size_t)(nb + ty + i) * HID + kb + tx] = f2bf(tile[tx][ty + i]);
}

// emb [NN][386] f32 -> ebf [NN][416] bf16 zero-padded
__global__ __launch_bounds__(256) void convert_emb(
    const float* __restrict__ emb, unsigned short* __restrict__ ebf)
{
    const int n = blockIdx.x;
    for (int k = threadIdx.x; k < KP_IN; k += 256)
        ebf[(size_t)n * KP_IN + k] =
            (k < IN_DIM) ? f2bf(emb[(size_t)n * IN_DIM + k]) : (unsigned short)0;
}

// ---------------------------------------------------------------------------
// ee tables, all layers in one launch: ee4[l][a][j] = Etab[a]@We[l] + be[l]
// ---------------------------------------------------------------------------
__global__ void ee_all_kernel(const float* __restrict__ Etab,
                              const float* __restrict__ We,
                              const float* __restrict__ be,
                              float* __restrict__ ee4)
{
    const int l = blockIdx.x, j = threadIdx.x;
    const float* Wel = We + (size_t)l * EDIM * HID;
    const float  bel = be[(size_t)l * HID + j];
    for (int a = 0; a < MAX_SP; ++a) {
        float s = bel;
        for (int kk = 0; kk < EDIM; ++kk)
            s = fmaf(Etab[a * EDIM + kk], Wel[(size_t)kk * HID + j], s);
        ee4[((size_t)l * MAX_SP + a) * HID + j] = s;
    }
}

// fused bias, 2048-wide: [0:512)=bq, [512:1024)=bk, [1024:1536)=bv, [1536:2048)=bs
__global__ void bias_fuse_kernel(const float* __restrict__ bq,
                                 const float* __restrict__ bk,
                                 const float* __restrict__ bv,
                                 const float* __restrict__ bs,
                                 float* __restrict__ bqkvs)
{
    const int i = blockIdx.x * 256 + threadIdx.x;   // < LL*2048
    const int l = i >> 11, r = i & 2047;
    float val = (r < 512)  ? bq[l * 512 + r]
              : (r < 1024) ? bk[l * 512 + r - 512]
              : (r < 1536) ? bv[l * 512 + r - 1024]
                           : bs[l * 512 + r - 1536];
    bqkvs[i] = val;
}

// ---------------------------------------------------------------------------
// CSR build: histogram -> scan -> scatter (src|aid packed into one int)
// ---------------------------------------------------------------------------
__global__ void hist_kernel(const int* __restrict__ dst, int* __restrict__ deg)
{
    int e = blockIdx.x * blockDim.x + threadIdx.x;
    if (e < EE_N) atomicAdd(&deg[dst[e]], 1);
}

__global__ __launch_bounds__(1024) void scan_kernel(
    const int* __restrict__ deg, int* __restrict__ row_ptr, int* __restrict__ cursor)
{
    __shared__ int sdata[1024];
    const int t = threadIdx.x;
    const int base = t * 32;   // 1024 * 32 == 32768
    int s = 0;
    for (int i = 0; i < 32; ++i) s += deg[base + i];
    sdata[t] = s;
    __syncthreads();
    for (int off = 1; off < 1024; off <<= 1) {
        int val = (t >= off) ? sdata[t - off] : 0;
        __syncthreads();
        sdata[t] += val;
        __syncthreads();
    }
    int run = sdata[t] - s;   // exclusive prefix
    for (int i = 0; i < 32; ++i) {
        row_ptr[base + i] = run;
        cursor[base + i]  = run;
        run += deg[base + i];
    }
    if (t == 1023) row_ptr[NN] = run;
}

__global__ void scatter_kernel(const int* __restrict__ src, const int* __restrict__ dst,
                               const int* __restrict__ aid, int* __restrict__ cursor,
                               int* __restrict__ csr_pack)
{
    int e = blockIdx.x * blockDim.x + threadIdx.x;
    if (e < EE_N) {
        int d = dst[e];
        int pos = atomicAdd(&cursor[d], 1);
        csr_pack[pos] = src[e] | (aid[e] << 16);
    }
}

// ---------------------------------------------------------------------------
// Attention over interleaved qkv rows (stride ld; k at +512, v at +1024).
// One wave per dst node; edge loop unrolled by 2 with dual accumulators for
// memory-level parallelism (4 independent gathers in flight per iteration).
// No online-max (|alpha| small; exact softmax ratio preserved).
// Writes the result over the node's q slot (own-row only).
// ---------------------------------------------------------------------------
__global__ __launch_bounds__(256) void attn_kernel(
    unsigned short* __restrict__ qkv, const float* __restrict__ ee,
    const int* __restrict__ row_ptr, const int* __restrict__ csr_pack, int ld)
{
    __shared__ float ees[MAX_SP * HID];
    const int t = threadIdx.x;
    for (int i = t; i < MAX_SP * HID; i += 256) ees[i] = ee[i];
    __syncthreads();

    const int wave = t >> 6, lane = t & 63;
    const int node = blockIdx.x * 4 + wave;
    const int off  = lane << 3;               // == h*64 + dg*8

    float qa[8];
    {
        uint4 qv = *reinterpret_cast<const uint4*>(&qkv[(size_t)node * ld + off]);
        unpack8(qv, qa);
    }

    float denomA = 0.f, denomB = 0.f;
    float accA[8] = {0.f,0.f,0.f,0.f,0.f,0.f,0.f,0.f};
    float accB[8] = {0.f,0.f,0.f,0.f,0.f,0.f,0.f,0.f};

    const int beg = row_ptr[node], end = row_ptr[node + 1];
    int i = beg;
    for (; i + 2 <= end; i += 2) {
        const int p0 = csr_pack[i];
        const int p1 = csr_pack[i + 1];
        const unsigned short* kp0 = &qkv[(size_t)(p0 & 0xFFFF) * ld + 512 + off];
        const unsigned short* kp1 = &qkv[(size_t)(p1 & 0xFFFF) * ld + 512 + off];
        const uint4 kv0 = *reinterpret_cast<const uint4*>(kp0);
        const uint4 vv0 = *reinterpret_cast<const uint4*>(kp0 + 512);
        const uint4 kv1 = *reinterpret_cast<const uint4*>(kp1);
        const uint4 vv1 = *reinterpret_cast<const uint4*>(kp1 + 512);
        const float* ep0 = &ees[(p0 >> 16) * HID + off];
        const float* ep1 = &ees[(p1 >> 16) * HID + off];

        float k0[8], k1[8];
        unpack8(kv0, k0); unpack8(kv1, k1);
        float d0 = 0.f, d1 = 0.f;
#pragma unroll
        for (int j = 0; j < 8; ++j) {
            d0 = fmaf(qa[j], k0[j] + ep0[j], d0);
            d1 = fmaf(qa[j], k1[j] + ep1[j], d1);
        }
        d0 += __shfl_xor(d0, 1); d1 += __shfl_xor(d1, 1);
        d0 += __shfl_xor(d0, 2); d1 += __shfl_xor(d1, 2);
        d0 += __shfl_xor(d0, 4); d1 += __shfl_xor(d1, 4);
        const float w0 = __expf(d0 * 0.125f);   // 1/sqrt(64)
        const float w1 = __expf(d1 * 0.125f);
        denomA += w0; denomB += w1;

        float v0[8], v1[8];
        unpack8(vv0, v0); unpack8(vv1, v1);
#pragma unroll
        for (int j = 0; j < 8; ++j) {
            accA[j] = fmaf(w0, v0[j] + ep0[j], accA[j]);
            accB[j] = fmaf(w1, v1[j] + ep1[j], accB[j]);
        }
    }
    if (i < end) {   // odd tail
        const int p0 = csr_pack[i];
        const unsigned short* kp0 = &qkv[(size_t)(p0 & 0xFFFF) * ld + 512 + off];
        const uint4 kv0 = *reinterpret_cast<const uint4*>(kp0);
        const uint4 vv0 = *reinterpret_cast<const uint4*>(kp0 + 512);
        const float* ep0 = &ees[(p0 >> 16) * HID + off];
        float k0[8];
        unpack8(kv0, k0);
        float d0 = 0.f;
#pragma unroll
        for (int j = 0; j < 8; ++j) d0 = fmaf(qa[j], k0[j] + ep0[j], d0);
        d0 += __shfl_xor(d0, 1);
        d0 += __shfl_xor(d0, 2);
        d0 += __shfl_xor(d0, 4);
        const float w0 = __expf(d0 * 0.125f);
        denomA += w0;
        float v0[8];
        unpack8(vv0, v0);
#pragma unroll
        for (int j = 0; j < 8; ++j) accA[j] = fmaf(w0, v0[j] + ep0[j], accA[j]);
    }

    const float denom = denomA + denomB;
    const float inv = (denom > 0.f) ? (1.f / denom) : 0.f;  // deg-0 node -> 0
    union { unsigned short us[8]; uint4 v4; } pk;
#pragma unroll
    for (int j = 0; j < 8; ++j) pk.us[j] = f2bf((accA[j] + accB[j]) * inv);
    *reinterpret_cast<uint4*>(&qkv[(size_t)node * ld + off]) = pk.v4;
}

// ---------------------------------------------------------------------------
// beta-gate + residual + LayerNorm; o = qkv q-slot, xr = qkv[xr_off] slot.
// Writes h (f32) AND hbf (bf16 shadow).
// ---------------------------------------------------------------------------
__global__ __launch_bounds__(256) void blend_ln_kernel(
    float* __restrict__ h, unsigned short* __restrict__ hbf,
    const unsigned short* __restrict__ qkv, const float* __restrict__ wbeta,
    const float* __restrict__ bbeta, const float* __restrict__ ln_g,
    const float* __restrict__ ln_b, int ld, int xr_off)
{
    const int t = threadIdx.x;
    const int wave = t >> 6, lane = t & 63;
    const int node = blockIdx.x * 4 + wave;
    const int off  = lane << 3;

    float o8[8], x8[8], h8[8];
    {
        uint4 a = *reinterpret_cast<const uint4*>(&qkv[(size_t)node * ld + off]);
        unpack8(a, o8);
        uint4 b = *reinterpret_cast<const uint4*>(&qkv[(size_t)node * ld + xr_off + off]);
        unpack8(b, x8);
        float4 c0 = *reinterpret_cast<const float4*>(&h[(size_t)node * HID + off]);
        float4 c1 = *reinterpret_cast<const float4*>(&h[(size_t)node * HID + off + 4]);
        h8[0]=c0.x; h8[1]=c0.y; h8[2]=c0.z; h8[3]=c0.w; h8[4]=c1.x; h8[5]=c1.y; h8[6]=c1.z; h8[7]=c1.w;
    }

    float p = 0.f;
#pragma unroll
    for (int j = 0; j < 8; ++j) {
        float w1 = wbeta[off + j];
        float w2 = wbeta[HID + off + j];
        float w3 = wbeta[2 * HID + off + j];
        p = fmaf(o8[j], w1 + w3, p);
        p = fmaf(x8[j], w2 - w3, p);
    }
#pragma unroll
    for (int m = 1; m <= 32; m <<= 1) p += __shfl_xor(p, m);
    const float beta = 1.f / (1.f + __expf(-(p + bbeta[0])));

    float y[8];
    float s = 0.f;
#pragma unroll
    for (int j = 0; j < 8; ++j) {
        y[j] = h8[j] + beta * x8[j] + (1.f - beta) * o8[j];
        s += y[j];
    }
#pragma unroll
    for (int m = 1; m <= 32; m <<= 1) s += __shfl_xor(s, m);
    const float mean = s * (1.f / HID);

    float vs = 0.f;
#pragma unroll
    for (int j = 0; j < 8; ++j) {
        float d = y[j] - mean;
        vs = fmaf(d, d, vs);
    }
#pragma unroll
    for (int m = 1; m <= 32; m <<= 1) vs += __shfl_xor(vs, m);
    const float rstd = rsqrtf(vs * (1.f / HID) + 1e-5f);

    float rr[8];
    union { unsigned short us[8]; uint4 v4; } pk;
#pragma unroll
    for (int j = 0; j < 8; ++j) {
        rr[j] = (y[j] - mean) * rstd * ln_g[off + j] + ln_b[off + j];
        pk.us[j] = f2bf(rr[j]);
    }
    float4 r0 = {rr[0], rr[1], rr[2], rr[3]};
    float4 r1 = {rr[4], rr[5], rr[6], rr[7]};
    *reinterpret_cast<float4*>(&h[(size_t)node * HID + off])     = r0;
    *reinterpret_cast<float4*>(&h[(size_t)node * HID + off + 4]) = r1;
    *reinterpret_cast<uint4*>(&hbf[(size_t)node * HID + off])    = pk.v4;
}

// ---------------------------------------------------------------------------
extern "C" void kernel_launch(void* const* d_in, const int* in_sizes, int n_in,
                              void* d_out, int out_size, void* d_ws, size_t ws_size,
                              hipStream_t stream)
{
    (void)in_sizes; (void)n_in; (void)out_size;
    const float* emb   = (const float*)d_in[0];
    const int*   eidx  = (const int*)d_in[1];
    const int*   aid   = (const int*)d_in[2];
    const float* Win   = (const float*)d_in[3];
    const float* bin_  = (const float*)d_in[4];
    const float* Etab  = (const float*)d_in[5];
    const float* Wq    = (const float*)d_in[6];
    const float* bq    = (const float*)d_in[7];
    const float* Wk    = (const float*)d_in[8];
    const float* bk    = (const float*)d_in[9];
    const float* Wv    = (const float*)d_in[10];
    const float* bv    = (const float*)d_in[11];
    const float* We    = (const float*)d_in[12];
    const float* be    = (const float*)d_in[13];
    const float* Ws    = (const float*)d_in[14];
    const float* bs    = (const float*)d_in[15];
    const float* Wbeta = (const float*)d_in[16];
    const float* bbeta = (const float*)d_in[17];
    const float* ln_g  = (const float*)d_in[18];
    const float* ln_b  = (const float*)d_in[19];
    const float* Wout  = (const float*)d_in[20];
    const float* bout  = (const float*)d_in[21];
    float* out = (float*)d_out;

    // Wide layout (q|k|v|s, ld=2048) needs ~234 MiB; fall back to the proven
    // 1536 layout + post-attn xr GEMM if ws_size is too small. ws_size is
    // constant across calls -> deterministic branch, graph-capture safe.
    const size_t fixed_tail =
        (size_t)HID * KP_IN * 2 + (size_t)16 * HID * HID * 2 +
        (size_t)OUT_DIM * HID * 2 + (size_t)LL * MAX_SP * HID * 4 +
        (size_t)LL * 2048 * 4 + (size_t)(NN + 4) * 4 + (size_t)NN * 4 * 2 +
        (size_t)EE_N * 4;
    const size_t base_sz = (size_t)NN * HID * 4 + (size_t)NN * HID * 2;
    const size_t need_wide = base_sz + (size_t)NN * 2048 * 2 + fixed_tail;
    const bool wide = (ws_size >= need_wide);
    const int  ld     = wide ? 2048 : 1536;
    const int  xr_off = wide ? 1536 : 512;

    char* w = (char*)d_ws;
    float* h            = (float*)w;           w += (size_t)NN * HID * 4;
    unsigned short* hbf = (unsigned short*)w;  w += (size_t)NN * HID * 2;
    unsigned short* qkv = (unsigned short*)w;  w += (size_t)NN * ld * 2;
    unsigned short* embbf = qkv;               // overlay: dead before layer-0 GEMM
    unsigned short* Winbf  = (unsigned short*)w; w += (size_t)HID * KP_IN * 2;
    unsigned short* Wlt    = (unsigned short*)w; w += (size_t)16 * HID * HID * 2;
    unsigned short* Woutbf = (unsigned short*)w; w += (size_t)OUT_DIM * HID * 2;
    float* ee4   = (float*)w;  w += (size_t)LL * MAX_SP * HID * 4;
    float* bqkvs = (float*)w;  w += (size_t)LL * 2048 * 4;
    int* row_ptr = (int*)w;    w += (NN + 4) * 4;
    int* cursor  = (int*)w;    w += NN * 4;
    int* deg     = (int*)w;    w += NN * 4;
    int* csr_pack = (int*)w;   w += EE_N * 4;

    const int* src = eidx;            // edge_index[0]
    const int* dst = eidx + EE_N;     // edge_index[1]

    // CSR build (inputs restored every call -> rebuild every launch)
    hipMemsetAsync(deg, 0, NN * sizeof(int), stream);
    hist_kernel<<<EE_N / 256, 256, 0, stream>>>(dst, deg);
    scan_kernel<<<1, 1024, 0, stream>>>(deg, row_ptr, cursor);
    scatter_kernel<<<EE_N / 256, 256, 0, stream>>>(src, dst, aid, cursor, csr_pack);

    // Weight/bias/ee prep (batched)
    dim3 tb(32, 8);
    convert_wt<<<dim3(HID / 32, KP_IN / 32), tb, 0, stream>>>(Win, Winbf, IN_DIM, HID, KP_IN);
    convert_wt_batch<<<dim3(16, 16, 16), tb, 0, stream>>>(Wq, Wk, Wv, Ws, Wlt);
    convert_wt<<<dim3(OUT_DIM / 32, HID / 32), tb, 0, stream>>>(Wout, Woutbf, HID, OUT_DIM, HID);
    convert_emb<<<NN, 256, 0, stream>>>(emb, embbf);
    ee_all_kernel<<<LL, HID, 0, stream>>>(Etab, We, be, ee4);
    bias_fuse_kernel<<<LL * 2048 / 256, 256, 0, stream>>>(bq, bk, bv, bs, bqkvs);

    // h = emb @ Win + bin   (f32 h + bf16 hbf)
    gemm_mfma<2><<<dim3(HID / 128, NN / 128), 256, 0, stream>>>(
        embbf, Winbf, bin_, h, hbf, NN, KP_IN, HID, HID);

    for (int l = 0; l < LL; ++l) {
        if (wide) {
            // fused q|k|v|s GEMM (xr computed alongside; s slot untouched by attn)
            gemm_mfma<1><<<dim3(2048 / 128, NN / 128), 256, 0, stream>>>(
                hbf, Wlt + (size_t)(l * 4) * HID * HID, bqkvs + (size_t)l * 2048,
                qkv, nullptr, NN, HID, 2048, 2048);
            attn_kernel<<<NN / 4, 256, 0, stream>>>(
                qkv, ee4 + (size_t)l * MAX_SP * HID, row_ptr, csr_pack, 2048);
        } else {
            // q|k|v GEMM; xr into the dead k slot after attn
            gemm_mfma<1><<<dim3(1536 / 128, NN / 128), 256, 0, stream>>>(
                hbf, Wlt + (size_t)(l * 4) * HID * HID, bqkvs + (size_t)l * 2048,
                qkv, nullptr, NN, HID, 1536, 1536);
            attn_kernel<<<NN / 4, 256, 0, stream>>>(
                qkv, ee4 + (size_t)l * MAX_SP * HID, row_ptr, csr_pack, 1536);
            gemm_mfma<1><<<dim3(HID / 128, NN / 128), 256, 0, stream>>>(
                hbf, Wlt + (size_t)(l * 4 + 3) * HID * HID, bs + (size_t)l * HID,
                qkv + 512, nullptr, NN, HID, HID, 1536);
        }
        blend_ln_kernel<<<NN / 4, 256, 0, stream>>>(
            h, hbf, qkv, Wbeta + (size_t)l * 3 * HID, bbeta + l,
            ln_g + (size_t)l * HID, ln_b + (size_t)l * HID, ld, xr_off);
    }

    // out = h @ Wout + bout  (f32)
    gemm_mfma<0><<<dim3(OUT_DIM / 128, NN / 128), 256, 0, stream>>>(
        hbf, Woutbf, bout, out, nullptr, NN, HID, OUT_DIM, OUT_DIM);
}